// Round 3
// baseline (282.623 us; speedup 1.0000x reference)
//
#include <hip/hip_runtime.h>
#include <math.h>

#define HH 1024
#define WW 1024
#define NCH 16
#define ROWS_PER_BLOCK 16
#define BLOCKS_PER_CH (HH / ROWS_PER_BLOCK) /* 64 */
#define NEG_INF (-INFINITY)

__device__ __forceinline__ bool better_f(float v1, int i1, float v2, int i2) {
    return (v1 > v2) || ((v1 == v2) && (i1 < i2));
}

// ---------------- Kernel A: NMS + per-block top-8 candidates + copy heatmap->out ----
__global__ __launch_bounds__(256) void kA(const float* __restrict__ hm,
                                          float* __restrict__ out,
                                          float* __restrict__ cand_val,
                                          int* __restrict__ cand_idx) {
    const int ch = blockIdx.y;
    const int r0 = blockIdx.x * ROWS_PER_BLOCK;
    const int tid = threadIdx.x;
    const int c0 = tid * 4;
    const float* hmc = hm + (size_t)ch * (size_t)(HH * WW);
    float* outc = out + (size_t)ch * (size_t)(HH * WW);

    float4 rawv[5], hxv[5];
    float tv[8]; int ti[8];
#pragma unroll
    for (int j = 0; j < 8; ++j) { tv[j] = NEG_INF; ti[j] = 0x7FFFFFFF; }

    auto loadrow = [&](int r, float4& rv, float4& hv) {
        if (r < 0 || r >= HH) {
            rv = make_float4(NEG_INF, NEG_INF, NEG_INF, NEG_INF);
            hv = rv;
            return;
        }
        const float* rp = hmc + (size_t)r * WW;
        float4 M = *(const float4*)(rp + c0);
        float4 L = (c0 >= 4) ? *(const float4*)(rp + c0 - 4)
                             : make_float4(NEG_INF, NEG_INF, NEG_INF, NEG_INF);
        float4 R = (c0 + 4 < WW) ? *(const float4*)(rp + c0 + 4)
                                 : make_float4(NEG_INF, NEG_INF, NEG_INF, NEG_INF);
        // cols c0-4+i; horizontal 5-max windows for output cols c0..c0+3
        float v2 = L.z, v3 = L.w, v4 = M.x, v5 = M.y, v6 = M.z, v7 = M.w, v8 = R.x, v9 = R.y;
        float a = fmaxf(v2, v3), b = fmaxf(v4, v5), c = fmaxf(v6, v7), d = fmaxf(v8, v9);
        hv.x = fmaxf(fmaxf(a, b), v6);
        hv.y = fmaxf(fmaxf(v3, b), c);
        hv.z = fmaxf(fmaxf(b, c), v8);
        hv.w = fmaxf(fmaxf(v5, c), d);
        rv = M;
    };

    auto push = [&](float v, int ix) {
        if (better_f(v, ix, tv[7], ti[7])) {
            tv[7] = v; ti[7] = ix;
#pragma unroll
            for (int j = 7; j >= 1; --j) {
                if (better_f(tv[j], ti[j], tv[j - 1], ti[j - 1])) {
                    float fv = tv[j]; tv[j] = tv[j - 1]; tv[j - 1] = fv;
                    int iv = ti[j]; ti[j] = ti[j - 1]; ti[j - 1] = iv;
                }
            }
        }
    };

    loadrow(r0 - 2, rawv[0], hxv[0]);
    loadrow(r0 - 1, rawv[1], hxv[1]);
    loadrow(r0 + 0, rawv[2], hxv[2]);
    loadrow(r0 + 1, rawv[3], hxv[3]);

#pragma unroll
    for (int i = 0; i < ROWS_PER_BLOCK; ++i) {
        const int r = r0 + i;
        loadrow(r + 2, rawv[(4 + i) % 5], hxv[(4 + i) % 5]);
        float4 p;
        p.x = fmaxf(fmaxf(fmaxf(hxv[0].x, hxv[1].x), fmaxf(hxv[2].x, hxv[3].x)), hxv[4].x);
        p.y = fmaxf(fmaxf(fmaxf(hxv[0].y, hxv[1].y), fmaxf(hxv[2].y, hxv[3].y)), hxv[4].y);
        p.z = fmaxf(fmaxf(fmaxf(hxv[0].z, hxv[1].z), fmaxf(hxv[2].z, hxv[3].z)), hxv[4].z);
        p.w = fmaxf(fmaxf(fmaxf(hxv[0].w, hxv[1].w), fmaxf(hxv[2].w, hxv[3].w)), hxv[4].w);
        float4 cen = rawv[(2 + i) % 5];
        *(float4*)(outc + (size_t)r * WW + c0) = cen;  // reweighted base = heatmap copy
        int base = r * WW + c0;
        push((cen.x == p.x) ? cen.x : 0.0f, base + 0);
        push((cen.y == p.y) ? cen.y : 0.0f, base + 1);
        push((cen.z == p.z) ? cen.z : 0.0f, base + 2);
        push((cen.w == p.w) ? cen.w : 0.0f, base + 3);
    }

    // block-wide exact top-8 merge: 8 rounds of argmax over per-thread sorted heads
    __shared__ float swv[4];
    __shared__ int swi[4];
    const int lane = tid & 63, wid = tid >> 6;
    const int slotbase = (ch * BLOCKS_PER_CH + blockIdx.x) * 8;
    for (int rnd = 0; rnd < 8; ++rnd) {
        float v = tv[0]; int ix = ti[0];
#pragma unroll
        for (int off = 32; off >= 1; off >>= 1) {
            float ov = __shfl_xor(v, off);
            int oi = __shfl_xor(ix, off);
            if (better_f(ov, oi, v, ix)) { v = ov; ix = oi; }
        }
        if (lane == 0) { swv[wid] = v; swi[wid] = ix; }
        __syncthreads();
        float bv = swv[0]; int bi = swi[0];
        if (better_f(swv[1], swi[1], bv, bi)) { bv = swv[1]; bi = swi[1]; }
        if (better_f(swv[2], swi[2], bv, bi)) { bv = swv[2]; bi = swi[2]; }
        if (better_f(swv[3], swi[3], bv, bi)) { bv = swv[3]; bi = swi[3]; }
        if (ti[0] == bi) {  // owner pops
#pragma unroll
            for (int j = 0; j < 7; ++j) { tv[j] = tv[j + 1]; ti[j] = ti[j + 1]; }
            tv[7] = NEG_INF; ti[7] = 0x7FFFFFFF;
        }
        if (tid == 0) { cand_val[slotbase + rnd] = bv; cand_idx[slotbase + rnd] = bi; }
        __syncthreads();
    }
}

// ---------------- Kernel B: per-channel final top-8 over 64 blocks x 8 candidates ---
__global__ __launch_bounds__(64) void kB(const float* __restrict__ cand_val,
                                         const int* __restrict__ cand_idx,
                                         float* __restrict__ out_pc,
                                         int* __restrict__ ws_rows,
                                         int* __restrict__ ws_cols) {
    const int ch = blockIdx.x;
    const int lane = threadIdx.x;
    float tv[8]; int ti[8];
    const float* cv = cand_val + (size_t)(ch * 64 + lane) * 8;
    const int* ci = cand_idx + (size_t)(ch * 64 + lane) * 8;
#pragma unroll
    for (int j = 0; j < 8; ++j) { tv[j] = cv[j]; ti[j] = ci[j]; }
    int mywin = 0;
    for (int rnd = 0; rnd < 8; ++rnd) {
        float v = tv[0]; int ix = ti[0];
#pragma unroll
        for (int off = 32; off >= 1; off >>= 1) {
            float ov = __shfl_xor(v, off);
            int oi = __shfl_xor(ix, off);
            if (better_f(ov, oi, v, ix)) { v = ov; ix = oi; }
        }
        if (ti[0] == ix) {
#pragma unroll
            for (int j = 0; j < 7; ++j) { tv[j] = tv[j + 1]; ti[j] = ti[j + 1]; }
            tv[7] = NEG_INF; ti[7] = 0x7FFFFFFF;
        }
        if (lane == rnd) mywin = ix;
    }
    if (lane < 8) {
        int row = mywin >> 10;
        int col = mywin & 1023;
        out_pc[ch * 16 + lane * 2 + 0] = (float)row;
        out_pc[ch * 16 + lane * 2 + 1] = (float)col;
        ws_rows[ch * 8 + lane] = row;
        ws_cols[ch * 8 + lane] = col;
    }
}

// ---------------- Kernel C: pooled feature (mean over V,Hf,Wf per channel) ----------
__global__ __launch_bounds__(256) void kC(const float* __restrict__ fm,
                                          float* __restrict__ pooled) {
    const int c = blockIdx.x;
    const int tid = threadIdx.x;
    float s = 0.f;
    for (int v = 0; v < 16; ++v) {
        const float* p = fm + (size_t)v * 131072 + (size_t)c * 1024;
#pragma unroll
        for (int i = 0; i < 4; ++i) s += p[tid + i * 256];
    }
#pragma unroll
    for (int off = 32; off >= 1; off >>= 1) s += __shfl_xor(s, off);
    __shared__ float red[4];
    if ((tid & 63) == 0) red[tid >> 6] = s;
    __syncthreads();
    if (tid == 0) pooled[c] = (red[0] + red[1] + red[2] + red[3]) * (1.0f / 16384.0f);
}

// ---------------- Kernel D0: curr embed + context + proto (tiny, 1 wave) ------------
__global__ __launch_bounds__(64) void kD0(const float* __restrict__ pooled,
                                          const float* __restrict__ prev,
                                          const float* __restrict__ p1w, const float* __restrict__ p1b,
                                          const float* __restrict__ p2w, const float* __restrict__ p2b,
                                          const float* __restrict__ cw, const float* __restrict__ cb,
                                          const float* __restrict__ sw, const float* __restrict__ sb,
                                          float* __restrict__ out_curr,
                                          float* __restrict__ ws_proto) {
    const int j = threadIdx.x;
    __shared__ float h1[64], cshr[64], ctx[64];
    float acc = p1b[j];
    for (int c = 0; c < 128; ++c) acc = fmaf(pooled[c], p1w[c * 64 + j], acc);
    h1[j] = fmaxf(acc, 0.f);
    __syncthreads();
    float e = p2b[j];
    for (int m = 0; m < 64; ++m) e = fmaf(h1[m], p2w[m * 64 + j], e);
    float sq = e * e;
#pragma unroll
    for (int off = 32; off >= 1; off >>= 1) sq += __shfl_xor(sq, off);
    float cur = e / fmaxf(sqrtf(sq), 1e-12f);
    out_curr[j] = cur;
    cshr[j] = cur;
    __syncthreads();
    float a3 = cb[j];
    for (int i = 0; i < 64; ++i) a3 = fmaf(prev[i], cw[i * 64 + j], a3);
    for (int i = 0; i < 64; ++i) a3 = fmaf(cshr[i], cw[(64 + i) * 64 + j], a3);
    ctx[j] = fmaxf(a3, 0.f);
    __syncthreads();
    float a4 = sb[j];
    for (int m = 0; m < 64; ++m) a4 = fmaf(ctx[m], sw[m * 64 + j], a4);
    ws_proto[j] = a4;
}

// ---------------- Kernel D1: per-view bilinear sample + MLP + scores + softmax ------
__global__ __launch_bounds__(64) void kD1(const float* __restrict__ fm,
                                          const int* __restrict__ ws_rows,
                                          const int* __restrict__ ws_cols,
                                          const float* __restrict__ n1w, const float* __restrict__ n1b,
                                          const float* __restrict__ n2w, const float* __restrict__ n2b,
                                          const float* __restrict__ ws_proto,
                                          float* __restrict__ out_ts,
                                          float* __restrict__ out_pe,
                                          float* __restrict__ ws_pw) {
    const int v = blockIdx.x;
    const int j = threadIdx.x;
    __shared__ float s[128], h1[64];
    const float proto_j = ws_proto[j];
    float myscore = 0.f;
    const float* base = fm + (size_t)v * 131072;

    for (int k = 0; k < 8; ++k) {
        int row = ws_rows[v * 8 + k], col = ws_cols[v * 8 + k];
        float ys = (float)row * 0.03125f, xs = (float)col * 0.03125f;
        int y0 = (int)floorf(ys), x0 = (int)floorf(xs);
        float wy = ys - (float)y0, wx = xs - (float)x0;
        float w00 = (1.f - wy) * (1.f - wx), w01 = (1.f - wy) * wx;
        float w10 = wy * (1.f - wx), w11 = wy * wx;

        auto samp = [&](int c) -> float {
            const float* fc = base + (size_t)c * 1024;
            float r = fc[y0 * 32 + x0] * w00;            // y0,x0 always in [0,31]
            if (x0 + 1 < 32) r += fc[y0 * 32 + x0 + 1] * w01;
            if (y0 + 1 < 32) {
                r += fc[(y0 + 1) * 32 + x0] * w10;
                if (x0 + 1 < 32) r += fc[(y0 + 1) * 32 + x0 + 1] * w11;
            }
            return r;
        };
        s[j] = samp(j);
        s[j + 64] = samp(j + 64);
        __syncthreads();
        float a = n1b[j];
        for (int c = 0; c < 128; ++c) a = fmaf(s[c], n1w[c * 64 + j], a);
        h1[j] = fmaxf(a, 0.f);
        __syncthreads();
        float e = n2b[j];
        for (int m = 0; m < 64; ++m) e = fmaf(h1[m], n2w[m * 64 + j], e);
        float sq = e * e;
#pragma unroll
        for (int off = 32; off >= 1; off >>= 1) sq += __shfl_xor(sq, off);
        float emb = e / fmaxf(sqrtf(sq), 1e-12f);
        out_pe[((size_t)v * 8 + k) * 64 + j] = emb;
        float sc = emb * proto_j;
#pragma unroll
        for (int off = 32; off >= 1; off >>= 1) sc += __shfl_xor(sc, off);
        if (j == k) myscore = sc;
        __syncthreads();
    }
    // softmax over 8 scores (held on lanes 0..7); all lanes compute m & sum uniformly
    float m = NEG_INF;
#pragma unroll
    for (int k = 0; k < 8; ++k) m = fmaxf(m, __shfl(myscore, k));
    float sum = 0.f;
#pragma unroll
    for (int k = 0; k < 8; ++k) sum += __expf(__shfl(myscore, k) - m);
    if (j < 8) {
        out_ts[v * 8 + j] = myscore;
        ws_pw[v * 8 + j] = __expf(myscore - m) / sum;
    }
}

// ---------------- Kernel F: sparse Gaussian patch add (65x65 per peak) --------------
__global__ __launch_bounds__(256) void kF(const int* __restrict__ ws_rows,
                                          const int* __restrict__ ws_cols,
                                          const float* __restrict__ ws_pw,
                                          float* __restrict__ out) {
    const int v = blockIdx.x;
    const int tid = threadIdx.x;
    float* oc = out + (size_t)v * (size_t)(HH * WW);
    const float inv2s2 = 1.0f / 18.0f;
    const int RAD = 32, SZ = 65;
    for (int k = 0; k < 8; ++k) {
        int r = ws_rows[v * 8 + k], c = ws_cols[v * 8 + k];
        float pw = ws_pw[v * 8 + k];
        for (int idx = tid; idx < SZ * SZ; idx += 256) {
            int dy = idx / SZ - RAD, dx = idx % SZ - RAD;
            int py = r + dy, px = c + dx;
            if (py >= 0 && py < HH && px >= 0 && px < WW) {
                float d2 = (float)(dy * dy + dx * dx);
                oc[(size_t)py * WW + px] += pw * __expf(-d2 * inv2s2);
            }
        }
        __syncthreads();  // patches of different k may overlap
    }
}

extern "C" void kernel_launch(void* const* d_in, const int* in_sizes, int n_in,
                              void* d_out, int out_size, void* d_ws, size_t ws_size,
                              hipStream_t stream) {
    (void)in_sizes; (void)n_in; (void)out_size; (void)ws_size;
    const float* hm   = (const float*)d_in[0];
    const float* fm   = (const float*)d_in[1];
    const float* prev = (const float*)d_in[2];
    const float* n1w  = (const float*)d_in[3];
    const float* n1b  = (const float*)d_in[4];
    const float* n2w  = (const float*)d_in[5];
    const float* n2b  = (const float*)d_in[6];
    const float* p1w  = (const float*)d_in[7];
    const float* p1b  = (const float*)d_in[8];
    const float* p2w  = (const float*)d_in[9];
    const float* p2b  = (const float*)d_in[10];
    const float* cw   = (const float*)d_in[11];
    const float* cb   = (const float*)d_in[12];
    const float* sw   = (const float*)d_in[13];
    const float* sb   = (const float*)d_in[14];
    float* out = (float*)d_out;

    char* ws = (char*)d_ws;
    float* cand_val  = (float*)(ws + 0);       // 16*64*8 f32 = 32768 B
    int*   cand_idx  = (int*)(ws + 32768);     // 32768 B
    int*   ws_rows   = (int*)(ws + 65536);     // 512 B
    int*   ws_cols   = (int*)(ws + 66048);     // 512 B
    float* ws_pooled = (float*)(ws + 66560);   // 512 B
    float* ws_proto  = (float*)(ws + 67072);   // 256 B
    float* ws_pw     = (float*)(ws + 67328);   // 512 B

    float* out_rew  = out;                 // 16*1024*1024
    float* out_curr = out + 16777216;      // 64
    float* out_pc   = out + 16777280;      // 256
    float* out_ts   = out + 16777536;      // 128
    float* out_pe   = out + 16777664;      // 8192

    kA<<<dim3(BLOCKS_PER_CH, NCH), 256, 0, stream>>>(hm, out_rew, cand_val, cand_idx);
    kB<<<NCH, 64, 0, stream>>>(cand_val, cand_idx, out_pc, ws_rows, ws_cols);
    kC<<<128, 256, 0, stream>>>(fm, ws_pooled);
    kD0<<<1, 64, 0, stream>>>(ws_pooled, prev, p1w, p1b, p2w, p2b, cw, cb, sw, sb,
                              out_curr, ws_proto);
    kD1<<<NCH, 64, 0, stream>>>(fm, ws_rows, ws_cols, n1w, n1b, n2w, n2b, ws_proto,
                                out_ts, out_pe, ws_pw);
    kF<<<NCH, 256, 0, stream>>>(ws_rows, ws_cols, ws_pw, out_rew);
}

// Round 5
// 206.761 us; speedup vs baseline: 1.3669x; 1.3669x over previous
//
#include <hip/hip_runtime.h>
#include <math.h>

#define HH 1024
#define WW 1024
#define NCH 16
#define ROWS_PER_BLOCK 8
#define BLOCKS_PER_CH (HH / ROWS_PER_BLOCK) /* 128 */
#define NEG_INF (-INFINITY)

__device__ __forceinline__ bool better_f(float v1, int i1, float v2, int i2) {
    return (v1 > v2) || ((v1 == v2) && (i1 < i2));
}

// ---------------- Kernel A: NMS + per-block top-8 candidates + copy heatmap->out ----
// 2048 blocks (8 rows each) -> 8192 waves = full grid occupancy.
__global__ __launch_bounds__(256) void kA(const float* __restrict__ hm,
                                          float* __restrict__ out,
                                          float* __restrict__ cand_val,
                                          int* __restrict__ cand_idx) {
    const int ch = blockIdx.y;
    const int r0 = blockIdx.x * ROWS_PER_BLOCK;
    const int tid = threadIdx.x;
    const int c0 = tid * 4;
    const float* hmc = hm + (size_t)ch * (size_t)(HH * WW);
    float* outc = out + (size_t)ch * (size_t)(HH * WW);

    float4 rawv[5], hxv[5];
    float tv[8]; int ti[8];
#pragma unroll
    for (int j = 0; j < 8; ++j) { tv[j] = NEG_INF; ti[j] = 0x7FFFFFFF; }

    auto loadrow = [&](int r, float4& rv, float4& hv) {
        if (r < 0 || r >= HH) {
            rv = make_float4(NEG_INF, NEG_INF, NEG_INF, NEG_INF);
            hv = rv;
            return;
        }
        const float* rp = hmc + (size_t)r * WW;
        float4 M = *(const float4*)(rp + c0);
        float4 L = (c0 >= 4) ? *(const float4*)(rp + c0 - 4)
                             : make_float4(NEG_INF, NEG_INF, NEG_INF, NEG_INF);
        float4 R = (c0 + 4 < WW) ? *(const float4*)(rp + c0 + 4)
                                 : make_float4(NEG_INF, NEG_INF, NEG_INF, NEG_INF);
        float v2 = L.z, v3 = L.w, v4 = M.x, v5 = M.y, v6 = M.z, v7 = M.w, v8 = R.x, v9 = R.y;
        float a = fmaxf(v2, v3), b = fmaxf(v4, v5), c = fmaxf(v6, v7), d = fmaxf(v8, v9);
        hv.x = fmaxf(fmaxf(a, b), v6);
        hv.y = fmaxf(fmaxf(v3, b), c);
        hv.z = fmaxf(fmaxf(b, c), v8);
        hv.w = fmaxf(fmaxf(v5, c), d);
        rv = M;
    };

    auto push = [&](float v, int ix) {
        if (better_f(v, ix, tv[7], ti[7])) {
            tv[7] = v; ti[7] = ix;
#pragma unroll
            for (int j = 7; j >= 1; --j) {
                if (better_f(tv[j], ti[j], tv[j - 1], ti[j - 1])) {
                    float fv = tv[j]; tv[j] = tv[j - 1]; tv[j - 1] = fv;
                    int iv = ti[j]; ti[j] = ti[j - 1]; ti[j - 1] = iv;
                }
            }
        }
    };

    loadrow(r0 - 2, rawv[0], hxv[0]);
    loadrow(r0 - 1, rawv[1], hxv[1]);
    loadrow(r0 + 0, rawv[2], hxv[2]);
    loadrow(r0 + 1, rawv[3], hxv[3]);

#pragma unroll
    for (int i = 0; i < ROWS_PER_BLOCK; ++i) {
        const int r = r0 + i;
        loadrow(r + 2, rawv[(4 + i) % 5], hxv[(4 + i) % 5]);
        float4 p;
        p.x = fmaxf(fmaxf(fmaxf(hxv[0].x, hxv[1].x), fmaxf(hxv[2].x, hxv[3].x)), hxv[4].x);
        p.y = fmaxf(fmaxf(fmaxf(hxv[0].y, hxv[1].y), fmaxf(hxv[2].y, hxv[3].y)), hxv[4].y);
        p.z = fmaxf(fmaxf(fmaxf(hxv[0].z, hxv[1].z), fmaxf(hxv[2].z, hxv[3].z)), hxv[4].z);
        p.w = fmaxf(fmaxf(fmaxf(hxv[0].w, hxv[1].w), fmaxf(hxv[2].w, hxv[3].w)), hxv[4].w);
        float4 cen = rawv[(2 + i) % 5];
        *(float4*)(outc + (size_t)r * WW + c0) = cen;  // reweighted base = heatmap copy
        int base = r * WW + c0;
        push((cen.x == p.x) ? cen.x : 0.0f, base + 0);
        push((cen.y == p.y) ? cen.y : 0.0f, base + 1);
        push((cen.z == p.z) ? cen.z : 0.0f, base + 2);
        push((cen.w == p.w) ? cen.w : 0.0f, base + 3);
    }

    // block-wide exact top-8: 8 rounds of argmax, 1 sync/round (ping-pong LDS),
    // winners carried in registers, single store at the end.
    __shared__ float swv[2][4];
    __shared__ int swi[2][4];
    const int lane = tid & 63, wid = tid >> 6;
    float wv = 0.f; int wi = 0;
    for (int rnd = 0; rnd < 8; ++rnd) {
        float v = tv[0]; int ix = ti[0];
#pragma unroll
        for (int off = 32; off >= 1; off >>= 1) {
            float ov = __shfl_xor(v, off);
            int oi = __shfl_xor(ix, off);
            if (better_f(ov, oi, v, ix)) { v = ov; ix = oi; }
        }
        if (lane == 0) { swv[rnd & 1][wid] = v; swi[rnd & 1][wid] = ix; }
        __syncthreads();
        float bv = swv[rnd & 1][0]; int bi = swi[rnd & 1][0];
        if (better_f(swv[rnd & 1][1], swi[rnd & 1][1], bv, bi)) { bv = swv[rnd & 1][1]; bi = swi[rnd & 1][1]; }
        if (better_f(swv[rnd & 1][2], swi[rnd & 1][2], bv, bi)) { bv = swv[rnd & 1][2]; bi = swi[rnd & 1][2]; }
        if (better_f(swv[rnd & 1][3], swi[rnd & 1][3], bv, bi)) { bv = swv[rnd & 1][3]; bi = swi[rnd & 1][3]; }
        if (ti[0] == bi) {  // owner pops
#pragma unroll
            for (int j = 0; j < 7; ++j) { tv[j] = tv[j + 1]; ti[j] = ti[j + 1]; }
            tv[7] = NEG_INF; ti[7] = 0x7FFFFFFF;
        }
        if (tid == rnd) { wv = bv; wi = bi; }
    }
    const int slotbase = (ch * BLOCKS_PER_CH + blockIdx.x) * 8;
    if (tid < 8) { cand_val[slotbase + tid] = wv; cand_idx[slotbase + tid] = wi; }
}

// ---------------- Kernel B: per-channel final top-8 over 128 blocks x 8 candidates --
__global__ __launch_bounds__(64) void kB(const float* __restrict__ cand_val,
                                         const int* __restrict__ cand_idx,
                                         float* __restrict__ out_pc,
                                         int* __restrict__ ws_rows,
                                         int* __restrict__ ws_cols) {
    const int ch = blockIdx.x;
    const int lane = threadIdx.x;
    float tv[8]; int ti[8];
#pragma unroll
    for (int j = 0; j < 8; ++j) { tv[j] = NEG_INF; ti[j] = 0x7FFFFFFF; }
    auto push = [&](float v, int ix) {
        if (better_f(v, ix, tv[7], ti[7])) {
            tv[7] = v; ti[7] = ix;
#pragma unroll
            for (int j = 7; j >= 1; --j) {
                if (better_f(tv[j], ti[j], tv[j - 1], ti[j - 1])) {
                    float fv = tv[j]; tv[j] = tv[j - 1]; tv[j - 1] = fv;
                    int iv = ti[j]; ti[j] = ti[j - 1]; ti[j - 1] = iv;
                }
            }
        }
    };
    const float* cv = cand_val + (size_t)ch * 1024 + lane * 16;
    const int* ci = cand_idx + (size_t)ch * 1024 + lane * 16;
#pragma unroll
    for (int j = 0; j < 16; ++j) push(cv[j], ci[j]);

    int mywin = 0;
    for (int rnd = 0; rnd < 8; ++rnd) {
        float v = tv[0]; int ix = ti[0];
#pragma unroll
        for (int off = 32; off >= 1; off >>= 1) {
            float ov = __shfl_xor(v, off);
            int oi = __shfl_xor(ix, off);
            if (better_f(ov, oi, v, ix)) { v = ov; ix = oi; }
        }
        if (ti[0] == ix) {
#pragma unroll
            for (int j = 0; j < 7; ++j) { tv[j] = tv[j + 1]; ti[j] = ti[j + 1]; }
            tv[7] = NEG_INF; ti[7] = 0x7FFFFFFF;
        }
        if (lane == rnd) mywin = ix;
    }
    if (lane < 8) {
        int row = mywin >> 10;
        int col = mywin & 1023;
        out_pc[ch * 16 + lane * 2 + 0] = (float)row;
        out_pc[ch * 16 + lane * 2 + 1] = (float)col;
        ws_rows[ch * 8 + lane] = row;
        ws_cols[ch * 8 + lane] = col;
    }
}

// ---------------- Kernel C: pooled feature (mean over V,Hf,Wf per channel) ----------
__global__ __launch_bounds__(256) void kC(const float* __restrict__ fm,
                                          float* __restrict__ pooled) {
    const int c = blockIdx.x;
    const int tid = threadIdx.x;
    float s = 0.f;
    for (int v = 0; v < 16; ++v) {
        const float* p = fm + (size_t)v * 131072 + (size_t)c * 1024;
#pragma unroll
        for (int i = 0; i < 4; ++i) s += p[tid + i * 256];
    }
#pragma unroll
    for (int off = 32; off >= 1; off >>= 1) s += __shfl_xor(s, off);
    __shared__ float red[4];
    if ((tid & 63) == 0) red[tid >> 6] = s;
    __syncthreads();
    if (tid == 0) pooled[c] = (red[0] + red[1] + red[2] + red[3]) * (1.0f / 16384.0f);
}

// ---------------- Kernel D0: curr embed + context + proto (tiny, 1 wave) ------------
__global__ __launch_bounds__(64) void kD0(const float* __restrict__ pooled,
                                          const float* __restrict__ prev,
                                          const float* __restrict__ p1w, const float* __restrict__ p1b,
                                          const float* __restrict__ p2w, const float* __restrict__ p2b,
                                          const float* __restrict__ cw, const float* __restrict__ cb,
                                          const float* __restrict__ sw, const float* __restrict__ sb,
                                          float* __restrict__ out_curr,
                                          float* __restrict__ ws_proto) {
    const int j = threadIdx.x;
    __shared__ float h1[64], cshr[64], ctx[64];
    float acc = p1b[j];
    for (int c = 0; c < 128; ++c) acc = fmaf(pooled[c], p1w[c * 64 + j], acc);
    h1[j] = fmaxf(acc, 0.f);
    __syncthreads();
    float e = p2b[j];
    for (int m = 0; m < 64; ++m) e = fmaf(h1[m], p2w[m * 64 + j], e);
    float sq = e * e;
#pragma unroll
    for (int off = 32; off >= 1; off >>= 1) sq += __shfl_xor(sq, off);
    float cur = e / fmaxf(sqrtf(sq), 1e-12f);
    out_curr[j] = cur;
    cshr[j] = cur;
    __syncthreads();
    float a3 = cb[j];
    for (int i = 0; i < 64; ++i) a3 = fmaf(prev[i], cw[i * 64 + j], a3);
    for (int i = 0; i < 64; ++i) a3 = fmaf(cshr[i], cw[(64 + i) * 64 + j], a3);
    ctx[j] = fmaxf(a3, 0.f);
    __syncthreads();
    float a4 = sb[j];
    for (int m = 0; m < 64; ++m) a4 = fmaf(ctx[m], sw[m * 64 + j], a4);
    ws_proto[j] = a4;
}

// ---------------- Kernel D1: per-(view,peak) bilinear sample + MLP + score ----------
// 128 blocks of 1 wave each.
__global__ __launch_bounds__(64) void kD1(const float* __restrict__ fm,
                                          const int* __restrict__ ws_rows,
                                          const int* __restrict__ ws_cols,
                                          const float* __restrict__ n1w, const float* __restrict__ n1b,
                                          const float* __restrict__ n2w, const float* __restrict__ n2b,
                                          const float* __restrict__ ws_proto,
                                          float* __restrict__ out_ts,
                                          float* __restrict__ out_pe) {
    const int p = blockIdx.x;
    const int v = p >> 3, k = p & 7;
    const int j = threadIdx.x;
    __shared__ float s[128], h1[64];
    const float* base = fm + (size_t)v * 131072;

    int row = ws_rows[v * 8 + k], col = ws_cols[v * 8 + k];
    float ys = (float)row * 0.03125f, xs = (float)col * 0.03125f;
    int y0 = (int)floorf(ys), x0 = (int)floorf(xs);
    float wy = ys - (float)y0, wx = xs - (float)x0;
    float w00 = (1.f - wy) * (1.f - wx), w01 = (1.f - wy) * wx;
    float w10 = wy * (1.f - wx), w11 = wy * wx;

    auto samp = [&](int c) -> float {
        const float* fc = base + (size_t)c * 1024;
        float r = fc[y0 * 32 + x0] * w00;  // y0,x0 always in [0,31]
        if (x0 + 1 < 32) r += fc[y0 * 32 + x0 + 1] * w01;
        if (y0 + 1 < 32) {
            r += fc[(y0 + 1) * 32 + x0] * w10;
            if (x0 + 1 < 32) r += fc[(y0 + 1) * 32 + x0 + 1] * w11;
        }
        return r;
    };
    s[j] = samp(j);
    s[j + 64] = samp(j + 64);
    __syncthreads();
    float a = n1b[j];
    for (int c = 0; c < 128; ++c) a = fmaf(s[c], n1w[c * 64 + j], a);
    h1[j] = fmaxf(a, 0.f);
    __syncthreads();
    float e = n2b[j];
    for (int m = 0; m < 64; ++m) e = fmaf(h1[m], n2w[m * 64 + j], e);
    float sq = e * e;
#pragma unroll
    for (int off = 32; off >= 1; off >>= 1) sq += __shfl_xor(sq, off);
    float emb = e / fmaxf(sqrtf(sq), 1e-12f);
    out_pe[(size_t)p * 64 + j] = emb;
    float sc = emb * ws_proto[j];
#pragma unroll
    for (int off = 32; off >= 1; off >>= 1) sc += __shfl_xor(sc, off);
    if (j == 0) out_ts[p] = sc;
}

// ---------------- Kernel F: per-(view,peak) Gaussian patch add (atomicAdd) ----------
// 128 blocks; softmax weight recomputed locally from the 8 scores of this view.
__global__ __launch_bounds__(256) void kF(const int* __restrict__ ws_rows,
                                          const int* __restrict__ ws_cols,
                                          const float* __restrict__ ts,
                                          float* __restrict__ out) {
    const int p = blockIdx.x;
    const int v = p >> 3, k = p & 7;
    const int tid = threadIdx.x;
    float t[8];
#pragma unroll
    for (int i = 0; i < 8; ++i) t[i] = ts[v * 8 + i];
    float m = t[0];
#pragma unroll
    for (int i = 1; i < 8; ++i) m = fmaxf(m, t[i]);
    float sum = 0.f;
#pragma unroll
    for (int i = 0; i < 8; ++i) sum += __expf(t[i] - m);
    const float pw = __expf(t[k] - m) / sum;

    const int r = ws_rows[v * 8 + k], c = ws_cols[v * 8 + k];
    float* oc = out + (size_t)v * (size_t)(HH * WW);
    const float inv2s2 = 1.0f / 18.0f;
    const int RAD = 32, SZ = 65;
    for (int idx = tid; idx < SZ * SZ; idx += 256) {
        int dy = idx / SZ - RAD, dx = idx % SZ - RAD;
        int py = r + dy, px = c + dx;
        if (py >= 0 && py < HH && px >= 0 && px < WW) {
            float d2 = (float)(dy * dy + dx * dx);
            atomicAdd(&oc[(size_t)py * WW + px], pw * __expf(-d2 * inv2s2));
        }
    }
}

extern "C" void kernel_launch(void* const* d_in, const int* in_sizes, int n_in,
                              void* d_out, int out_size, void* d_ws, size_t ws_size,
                              hipStream_t stream) {
    (void)in_sizes; (void)n_in; (void)out_size; (void)ws_size;
    const float* hm   = (const float*)d_in[0];
    const float* fm   = (const float*)d_in[1];
    const float* prev = (const float*)d_in[2];
    const float* n1w  = (const float*)d_in[3];
    const float* n1b  = (const float*)d_in[4];
    const float* n2w  = (const float*)d_in[5];
    const float* n2b  = (const float*)d_in[6];
    const float* p1w  = (const float*)d_in[7];
    const float* p1b  = (const float*)d_in[8];
    const float* p2w  = (const float*)d_in[9];
    const float* p2b  = (const float*)d_in[10];
    const float* cw   = (const float*)d_in[11];
    const float* cb   = (const float*)d_in[12];
    const float* sw   = (const float*)d_in[13];
    const float* sb   = (const float*)d_in[14];
    float* out = (float*)d_out;

    char* ws = (char*)d_ws;
    float* cand_val  = (float*)(ws + 0);        // 16*128*8 f32 = 65536 B
    int*   cand_idx  = (int*)(ws + 65536);      // 65536 B
    int*   ws_rows   = (int*)(ws + 131072);     // 512 B
    int*   ws_cols   = (int*)(ws + 131584);     // 512 B
    float* ws_pooled = (float*)(ws + 132096);   // 512 B
    float* ws_proto  = (float*)(ws + 132608);   // 256 B

    float* out_rew  = out;                 // 16*1024*1024
    float* out_curr = out + 16777216;      // 64
    float* out_pc   = out + 16777280;      // 256
    float* out_ts   = out + 16777536;      // 128
    float* out_pe   = out + 16777664;      // 8192

    kA<<<dim3(BLOCKS_PER_CH, NCH), 256, 0, stream>>>(hm, out_rew, cand_val, cand_idx);
    kB<<<NCH, 64, 0, stream>>>(cand_val, cand_idx, out_pc, ws_rows, ws_cols);
    kC<<<128, 256, 0, stream>>>(fm, ws_pooled);
    kD0<<<1, 64, 0, stream>>>(ws_pooled, prev, p1w, p1b, p2w, p2b, cw, cb, sw, sb,
                              out_curr, ws_proto);
    kD1<<<128, 64, 0, stream>>>(fm, ws_rows, ws_cols, n1w, n1b, n2w, n2b, ws_proto,
                                out_ts, out_pe);
    kF<<<128, 256, 0, stream>>>(ws_rows, ws_cols, out_ts, out_rew);
}